// Round 14
// baseline (370.178 us; speedup 1.0000x reference)
//
#include <hip/hip_runtime.h>

// out[s][o] = sum_i x[s][i] * dq(w[o][i]); int4 group quant, group=256, scale=max(absmax/7,1e-9)
// x: [16,4096] f32, w: [14336,4096] f32 (235 MB streamed once), out: [16,14336] f32
//
// R15 = R14/R6 champion + ping-pong depth-2 w prefetch. SINGLE variable:
// the prefetch schedule. R6 waited for wnext at the BOTTOM of the issuing
// iteration (~840cyc cover; HBM latency ~900cyc, and FETCH=117MB says ~half
// of w misses L3). Ping-pong: even groups live in bufA, odd in bufB; each
// buffer is reloaded right AFTER its FMA section and consumed two
// single-iterations later -> ~1.3-1.7 iters of cover, ZERO extra registers
// (still 2x16 buffer regs; the R7 >128-reg spill mode structurally excluded).
// Register w-prefetches survive the phase barriers (only global_load_lds
// forces a vmcnt(0) drain at s_barrier).
// Occupancy lesson (R8-R13): measured OccupancyPercent pinned at 26-36%
// regardless of VGPR/LDS/grid caps -> dispatcher never fills the chip; the
// usable axis is per-wave serial-stall minimization, which is why the R6
// structure (x on LDS pipe, w on VMEM pipe, RPW=4 amortization) wins.
// Held from R14: RPW=4, NWAVE=7 (448thr), PH_I=1024 (64KB LDS), DPP absmax,
// '#pragma unroll 1' on the pair loop (R7: unrolling hoisted loads -> 263MB
// scratch), value-split epilogue. Tripwires: WRITE_SIZE ~0.9MB, VGPR <=128.

constexpr int O_DIM  = 14336;
constexpr int I_DIM  = 4096;
constexpr int S_DIM  = 16;
constexpr int GS     = 256;           // quant group size
constexpr int NG     = I_DIM / GS;    // 16 groups
constexpr int RPW    = 4;             // rows per wave
constexpr int NWAVE  = 7;             // waves per block
constexpr int NTHR   = 64 * NWAVE;    // 448
constexpr int RPB    = RPW * NWAVE;   // 28 rows/block -> 512 blocks = 2/CU
constexpr int PH_I   = 1024;          // i-extent per x staging phase
constexpr int NPH    = I_DIM / PH_I;  // 4 phases
constexpr int GPP    = PH_I / GS;     // 4 groups per phase (2 ping-pong pairs)

// wave64 max-reduce on the VALU pipe (validated correct in R5..R14 runs):
// 4x row_shr + row_bcast15 + row_bcast31, readlane(63) -> wave-uniform SGPR.
// Inputs >= 0, so bound_ctrl=true zero-fill is identity for max.
__device__ __forceinline__ float wave_max_dpp(float x) {
    int v = __float_as_int(x);
    int t;
    t = __builtin_amdgcn_update_dpp(0, v, 0x111, 0xf, 0xf, true); // row_shr:1
    v = __float_as_int(fmaxf(__int_as_float(v), __int_as_float(t)));
    t = __builtin_amdgcn_update_dpp(0, v, 0x112, 0xf, 0xf, true); // row_shr:2
    v = __float_as_int(fmaxf(__int_as_float(v), __int_as_float(t)));
    t = __builtin_amdgcn_update_dpp(0, v, 0x114, 0xf, 0xf, true); // row_shr:4
    v = __float_as_int(fmaxf(__int_as_float(v), __int_as_float(t)));
    t = __builtin_amdgcn_update_dpp(0, v, 0x118, 0xf, 0xf, true); // row_shr:8
    v = __float_as_int(fmaxf(__int_as_float(v), __int_as_float(t)));
    t = __builtin_amdgcn_update_dpp(0, v, 0x142, 0xf, 0xf, true); // row_bcast:15
    v = __float_as_int(fmaxf(__int_as_float(v), __int_as_float(t)));
    t = __builtin_amdgcn_update_dpp(0, v, 0x143, 0xf, 0xf, true); // row_bcast:31
    v = __float_as_int(fmaxf(__int_as_float(v), __int_as_float(t)));
    return __int_as_float(__builtin_amdgcn_readlane(v, 63));
}

// dequant a 4-row group fragment in place (absmax via DPP, exact-div invs)
__device__ __forceinline__ void dequant_frag(float4* wq) {
#pragma unroll
    for (int r = 0; r < RPW; ++r) {
        float4 v = wq[r];
        float m = fmaxf(fmaxf(fabsf(v.x), fabsf(v.y)),
                        fmaxf(fabsf(v.z), fabsf(v.w)));
        m = wave_max_dpp(m);
        float scale = fmaxf(m * (1.0f / 7.0f), 1e-9f);
        float invs  = 1.0f / scale;
        // clamp provably dead: scale >= absmax/7 => |v*invs| <= 7
        wq[r].x = rintf(v.x * invs) * scale;
        wq[r].y = rintf(v.y * invs) * scale;
        wq[r].z = rintf(v.z * invs) * scale;
        wq[r].w = rintf(v.w * invs) * scale;
    }
}

__global__ __launch_bounds__(NTHR)
void qlin_kernel(const float* __restrict__ x,
                 const float* __restrict__ w,
                 float* __restrict__ out)
{
    __shared__ float xs[S_DIM][PH_I];   // 64 KB -> LDS caps at 2 blocks/CU

    const int tid  = threadIdx.x;
    const int lane = tid & 63;
    const int wv   = tid >> 6;          // 0..6
    const int row0 = blockIdx.x * RPB + wv * RPW;

    const float* wp = w + (size_t)row0 * I_DIM + lane * 4;

    float acc[RPW][S_DIM];
#pragma unroll
    for (int r = 0; r < RPW; ++r)
#pragma unroll
        for (int s = 0; s < S_DIM; ++s) acc[r][s] = 0.0f;

    // ping-pong buffers: bA holds even groups, bB holds odd groups.
    float4 bA[RPW], bB[RPW];
#pragma unroll
    for (int r = 0; r < RPW; ++r)
        bA[r] = *reinterpret_cast<const float4*>(wp + (size_t)r * I_DIM);
#pragma unroll
    for (int r = 0; r < RPW; ++r)
        bB[r] = *reinterpret_cast<const float4*>(wp + (size_t)r * I_DIM + GS);

    for (int p = 0; p < NPH; ++p) {
        // ---- stage x[:, p*1024 .. +1024) into LDS (4096 float4 / 448 thr) ----
        if (p) __syncthreads();         // all waves done reading phase p-1
        for (int j = tid; j < S_DIM * (PH_I / 4); j += NTHR) {
            const int s  = j >> 8;          // float4-slot / 256-per-row
            const int i4 = (j & 255) * 4;
            *reinterpret_cast<float4*>(&xs[s][i4]) =
                *reinterpret_cast<const float4*>(
                    &x[(size_t)s * I_DIM + p * PH_I + i4]);
        }
        __syncthreads();

        // unroll 1: R7 lesson — cross-iteration load hoisting spilled 263 MB.
#pragma unroll 1
        for (int gp = 0; gp < GPP / 2; ++gp) {
            const int G = p * GPP + 2 * gp;     // even group of this pair

            // ---- A: group G (loaded ~2 single-iterations ago) ----
            dequant_frag(bA);
            {
                const int xb = (2 * gp) * GS + lane * 4;
#pragma unroll
                for (int s = 0; s < S_DIM; ++s) {
                    float4 xv = *reinterpret_cast<const float4*>(&xs[s][xb]);
#pragma unroll
                    for (int r = 0; r < RPW; ++r) {
                        acc[r][s] = fmaf(bA[r].x, xv.x, acc[r][s]);
                        acc[r][s] = fmaf(bA[r].y, xv.y, acc[r][s]);
                        acc[r][s] = fmaf(bA[r].z, xv.z, acc[r][s]);
                        acc[r][s] = fmaf(bA[r].w, xv.w, acc[r][s]);
                    }
                }
            }
            // reload A for G+2 — consumed two single-iterations from now.
            if (G + 2 < NG) {
#pragma unroll
                for (int r = 0; r < RPW; ++r)
                    bA[r] = *reinterpret_cast<const float4*>(
                        wp + (size_t)r * I_DIM + (G + 2) * GS);
            }

            // ---- B: group G+1 ----
            dequant_frag(bB);
            {
                const int xb = (2 * gp + 1) * GS + lane * 4;
#pragma unroll
                for (int s = 0; s < S_DIM; ++s) {
                    float4 xv = *reinterpret_cast<const float4*>(&xs[s][xb]);
#pragma unroll
                    for (int r = 0; r < RPW; ++r) {
                        acc[r][s] = fmaf(bB[r].x, xv.x, acc[r][s]);
                        acc[r][s] = fmaf(bB[r].y, xv.y, acc[r][s]);
                        acc[r][s] = fmaf(bB[r].z, xv.z, acc[r][s]);
                        acc[r][s] = fmaf(bB[r].w, xv.w, acc[r][s]);
                    }
                }
            }
            // reload B for G+3.
            if (G + 3 < NG) {
#pragma unroll
                for (int r = 0; r < RPW; ++r)
                    bB[r] = *reinterpret_cast<const float4*>(
                        wp + (size_t)r * I_DIM + (G + 3) * GS);
            }
        }
    }

    // ---- epilogue: reduce 64 accs across 64 lanes in 63 shuffles ----
    // value-splitting butterfly; lane l ends with the sum of a[l], l=(r<<4)|s.
    float a[64];
#pragma unroll
    for (int r = 0; r < RPW; ++r)
#pragma unroll
        for (int s = 0; s < S_DIM; ++s) a[(r << 4) | s] = acc[r][s];

#pragma unroll
    for (int m = 32; m >= 1; m >>= 1) {
        const bool hi = (lane & m) != 0;
#pragma unroll
        for (int j = 0; j < m; ++j) {
            float snd  = hi ? a[j] : a[j + m];
            float rcv  = __shfl_xor(snd, m, 64);
            float kept = hi ? a[j + m] : a[j];
            a[j] = kept + rcv;
        }
    }
    {
        const int r = lane >> 4, s = lane & 15;
        out[s * O_DIM + (row0 + r)] = a[0];
    }
}

extern "C" void kernel_launch(void* const* d_in, const int* in_sizes, int n_in,
                              void* d_out, int out_size, void* d_ws, size_t ws_size,
                              hipStream_t stream) {
    const float* x = (const float*)d_in[0];   // 1*16*4096
    const float* w = (const float*)d_in[1];   // 14336*4096
    float* out = (float*)d_out;               // 16*14336
    dim3 grid(O_DIM / RPB);                   // 512 blocks -> 2 per CU
    dim3 block(NTHR);                         // 448 = 7 waves
    qlin_kernel<<<grid, block, 0, stream>>>(x, w, out);
}